// Round 1
// baseline (1590.139 us; speedup 1.0000x reference)
//
#include <hip/hip_runtime.h>
#include <hip/hip_bf16.h>
#include <cstdint>
#include <cstddef>

// Problem constants
#define MM 2048     // B*T
#define HH 1024     // H
#define EE 50000    // episodic memory size
#define EH 25088    // E half, padded to multiple of 128 (2*EH = 50176 >= EE)
#define KC 2048     // 2*H (concat dim)

typedef __attribute__((ext_vector_type(8))) short short8;   // 8 bf16 (4 VGPRs) MFMA A/B frag
typedef __attribute__((ext_vector_type(4))) float floatx4;  // MFMA C/D frag
typedef unsigned short ushort_t;

// ---------- helpers ----------
__device__ __forceinline__ ushort_t f2b(float f) {
    union { float f; uint32_t u; } c; c.f = f;
    uint32_t u = c.u;
    u += 0x7fffu + ((u >> 16) & 1u);   // round-to-nearest-even
    return (ushort_t)(u >> 16);
}
__device__ __forceinline__ float b2f(ushort_t h) {
    union { uint32_t u; float f; } c; c.u = ((uint32_t)h) << 16;
    return c.f;
}

// global -> LDS direct DMA, 16 bytes per lane. LDS dest must be the
// wave-uniform base; HW adds lane*16. (cdna_hip_programming.md §5)
__device__ __forceinline__ void gl2lds16(const ushort_t* g, ushort_t* l) {
    __builtin_amdgcn_global_load_lds(
        (const __attribute__((address_space(1))) void*)g,
        (__attribute__((address_space(3))) void*)l, 16, 0, 0);
}

// ---------- K0: convert x (fp32) -> bf16 ----------
__global__ __launch_bounds__(256) void k0_convert_x(const float* __restrict__ x,
                                                    ushort_t* __restrict__ xb) {
    int i = (blockIdx.x * 256 + threadIdx.x) * 8;  // grid covers MM*HH exactly
    float4 v0 = *(const float4*)(x + i);
    float4 v1 = *(const float4*)(x + i + 4);
    union { uint4 v; ushort_t u[8]; } pk;
    pk.u[0] = f2b(v0.x); pk.u[1] = f2b(v0.y); pk.u[2] = f2b(v0.z); pk.u[3] = f2b(v0.w);
    pk.u[4] = f2b(v1.x); pk.u[5] = f2b(v1.y); pk.u[6] = f2b(v1.z); pk.u[7] = f2b(v1.w);
    *(uint4*)(xb + i) = pk.v;
}

// ---------- KW: convert one E-half of W_epi (fp32) -> bf16, pad rows -> 0 ----------
// grid EH*HH/8/256 = 12544, block 256
__global__ __launch_bounds__(256) void kw_conv(const float* __restrict__ W,
                                               ushort_t* __restrict__ Wb, int ebase) {
    const size_t i = ((size_t)blockIdx.x * 256 + threadIdx.x) * 8;
    const int row = (int)(i >> 10);        // /HH
    const int e_gl = ebase + row;
    union { uint4 v; ushort_t u[8]; } pk;
    if (e_gl < EE) {
        const float* p = W + (size_t)e_gl * HH + (i & 1023);
        float4 a = *(const float4*)p;
        float4 b = *(const float4*)(p + 4);
        pk.u[0] = f2b(a.x); pk.u[1] = f2b(a.y); pk.u[2] = f2b(a.z); pk.u[3] = f2b(a.w);
        pk.u[4] = f2b(b.x); pk.u[5] = f2b(b.y); pk.u[6] = f2b(b.z); pk.u[7] = f2b(b.w);
    } else {
        pk.v = make_uint4(0u, 0u, 0u, 0u);
    }
    *(uint4*)(Wb + i) = pk.v;
}

// ---------- KT: transpose+convert one E-half of epi_mem -> mT[h][e] bf16 ----------
// tile 64(e) x 64(h); grid (EH/64=392, HH/64=16), block 256
__global__ __launch_bounds__(256) void km_transpose(const float* __restrict__ mem,
                                                    ushort_t* __restrict__ mT, int ebase) {
    __shared__ ushort_t sT[64][72];
    const int e0 = blockIdx.x * 64;
    const int h0 = blockIdx.y * 64;
    const int t = threadIdx.x;
    const int ty = t >> 4;          // 0..15
    const int tx = (t & 15) * 4;    // 0..60
#pragma unroll
    for (int p = 0; p < 4; p++) {
        const int er = p * 16 + ty;
        const int e_gl = ebase + e0 + er;
        float4 v = make_float4(0.f, 0.f, 0.f, 0.f);
        if (e_gl < EE) v = *(const float4*)(mem + (size_t)e_gl * HH + h0 + tx);
        sT[er][tx + 0] = f2b(v.x); sT[er][tx + 1] = f2b(v.y);
        sT[er][tx + 2] = f2b(v.z); sT[er][tx + 3] = f2b(v.w);
    }
    __syncthreads();
    const int hr = t >> 3;          // 0..31
    const int ec = (t & 7) * 8;     // 0..56
#pragma unroll
    for (int p = 0; p < 2; p++) {
        const int h = hr + p * 32;
        union { uint4 v; ushort_t u[8]; } pk;
#pragma unroll
        for (int j = 0; j < 8; j++) pk.u[j] = sT[ec + j][h];
        *(uint4*)(mT + (size_t)(h0 + h) * EH + e0 + ec) = pk.v;
    }
}

// ---------- G1: P = exp(xb @ Wb^T + b), den += row sums ----------
// m97 structure: 128x128 tile, BK=32, 4 waves x (4x4 frags), global_load_lds.
// grid (16, 196), block 256
__global__ __launch_bounds__(256) void g1_logits(const ushort_t* __restrict__ xb,
                                                 const ushort_t* __restrict__ Wb,
                                                 const float* __restrict__ bias,
                                                 ushort_t* __restrict__ P,
                                                 float* __restrict__ den, int ebase) {
    __shared__ ushort_t sA[128 * 32];
    __shared__ ushort_t sB[128 * 32];
    const int m0 = blockIdx.x * 128;
    const int e0 = blockIdx.y * 128;
    const int t = threadIdx.x;
    const int w = t >> 6, l = t & 63;
    const int ml = l & 15, q = l >> 4;
    const int wm = (w >> 1) * 64;
    const int wn = (w & 1) * 64;
    const int srow = t >> 2;        // 0..63
    const int scol = (t & 3) * 8;   // 0,8,16,24

    floatx4 acc[4][4];
#pragma unroll
    for (int i = 0; i < 4; i++)
#pragma unroll
        for (int j = 0; j < 4; j++) acc[i][j] = (floatx4)(0.0f);

    const ushort_t* Ag  = xb + (size_t)(m0 + srow) * HH + scol;
    const ushort_t* Ag2 = Ag + (size_t)64 * HH;
    const ushort_t* Bg  = Wb + (size_t)(e0 + srow) * HH + scol;
    const ushort_t* Bg2 = Bg + (size_t)64 * HH;
    ushort_t* lA  = &sA[(w * 64) * 8];          // wave-uniform bases
    ushort_t* lA2 = &sA[(256 + w * 64) * 8];
    ushort_t* lB  = &sB[(w * 64) * 8];
    ushort_t* lB2 = &sB[(256 + w * 64) * 8];

    for (int k0 = 0; k0 < HH; k0 += 32) {
        gl2lds16(Ag + k0, lA);
        gl2lds16(Ag2 + k0, lA2);
        gl2lds16(Bg + k0, lB);
        gl2lds16(Bg2 + k0, lB2);
        __syncthreads();            // drains vmcnt(0) -> tiles ready
        short8 af[4], bf[4];
#pragma unroll
        for (int im = 0; im < 4; im++)
            af[im] = *(const short8*)&sA[(wm + im * 16 + ml) * 32 + q * 8];
#pragma unroll
        for (int ie = 0; ie < 4; ie++)
            bf[ie] = *(const short8*)&sB[(wn + ie * 16 + ml) * 32 + q * 8];
#pragma unroll
        for (int im = 0; im < 4; im++)
#pragma unroll
            for (int ie = 0; ie < 4; ie++)
                acc[im][ie] = __builtin_amdgcn_mfma_f32_16x16x32_bf16(af[im], bf[ie], acc[im][ie], 0, 0, 0);
        __syncthreads();            // all reads done before next staging
    }

    float rs[4][4];
#pragma unroll
    for (int im = 0; im < 4; im++)
#pragma unroll
        for (int r = 0; r < 4; r++) rs[im][r] = 0.0f;

#pragma unroll
    for (int ie = 0; ie < 4; ie++) {
        const int e_loc = e0 + wn + ie * 16 + ml;
        const int e_gl = ebase + e_loc;
        const bool valid = (e_gl < EE);
        const float bb = valid ? bias[e_gl] : 0.0f;
#pragma unroll
        for (int im = 0; im < 4; im++) {
            const size_t rb = (size_t)(m0 + wm + im * 16 + q * 4) * EH + e_loc;
#pragma unroll
            for (int r = 0; r < 4; r++) {
                float p = valid ? __expf(acc[im][ie][r] + bb) : 0.0f;
                P[rb + (size_t)r * EH] = f2b(p);
                rs[im][r] += p;
            }
        }
    }
    // reduce row sums across the 16 col-lanes (ml), then one atomic per row
#pragma unroll
    for (int im = 0; im < 4; im++)
#pragma unroll
        for (int r = 0; r < 4; r++) {
            float v = rs[im][r];
            v += __shfl_xor(v, 1); v += __shfl_xor(v, 2);
            v += __shfl_xor(v, 4); v += __shfl_xor(v, 8);
            rs[im][r] = v;
        }
    if (ml == 0) {
#pragma unroll
        for (int im = 0; im < 4; im++)
#pragma unroll
            for (int r = 0; r < 4; r++)
                atomicAdd(&den[m0 + wm + im * 16 + q * 4 + r], rs[im][r]);
    }
}

// ---------- G2: num += P @ mT^T (split-K atomics) ----------
// Same m97 structure; A = P [M][EH], B = mT [H][EH]; K split 4 ways.
// grid (16, 8, 4), block 256
__global__ __launch_bounds__(256) void g2_pv(const ushort_t* __restrict__ P,
                                             const ushort_t* __restrict__ mT,
                                             float* __restrict__ num) {
    __shared__ ushort_t sA[128 * 32];
    __shared__ ushort_t sB[128 * 32];
    const int m0 = blockIdx.x * 128;
    const int h0 = blockIdx.y * 128;
    const int kbase = blockIdx.z * (EH / 4);   // 6272 = 196 K-steps
    const int t = threadIdx.x;
    const int w = t >> 6, l = t & 63;
    const int ml = l & 15, q = l >> 4;
    const int wm = (w >> 1) * 64;
    const int wn = (w & 1) * 64;
    const int srow = t >> 2;
    const int scol = (t & 3) * 8;

    floatx4 acc[4][4];
#pragma unroll
    for (int i = 0; i < 4; i++)
#pragma unroll
        for (int j = 0; j < 4; j++) acc[i][j] = (floatx4)(0.0f);

    const ushort_t* Ag  = P + (size_t)(m0 + srow) * EH + kbase + scol;
    const ushort_t* Ag2 = Ag + (size_t)64 * EH;
    const ushort_t* Bg  = mT + (size_t)(h0 + srow) * EH + kbase + scol;
    const ushort_t* Bg2 = Bg + (size_t)64 * EH;
    ushort_t* lA  = &sA[(w * 64) * 8];
    ushort_t* lA2 = &sA[(256 + w * 64) * 8];
    ushort_t* lB  = &sB[(w * 64) * 8];
    ushort_t* lB2 = &sB[(256 + w * 64) * 8];

    for (int k0 = 0; k0 < EH / 4; k0 += 32) {
        gl2lds16(Ag + k0, lA);
        gl2lds16(Ag2 + k0, lA2);
        gl2lds16(Bg + k0, lB);
        gl2lds16(Bg2 + k0, lB2);
        __syncthreads();
        short8 af[4], bf[4];
#pragma unroll
        for (int im = 0; im < 4; im++)
            af[im] = *(const short8*)&sA[(wm + im * 16 + ml) * 32 + q * 8];
#pragma unroll
        for (int ie = 0; ie < 4; ie++)
            bf[ie] = *(const short8*)&sB[(wn + ie * 16 + ml) * 32 + q * 8];
#pragma unroll
        for (int im = 0; im < 4; im++)
#pragma unroll
            for (int ie = 0; ie < 4; ie++)
                acc[im][ie] = __builtin_amdgcn_mfma_f32_16x16x32_bf16(af[im], bf[ie], acc[im][ie], 0, 0, 0);
        __syncthreads();
    }

#pragma unroll
    for (int im = 0; im < 4; im++) {
        const int mg = m0 + wm + im * 16 + q * 4;
#pragma unroll
        for (int ie = 0; ie < 4; ie++) {
            const int hg = h0 + wn + ie * 16 + ml;
#pragma unroll
            for (int r = 0; r < 4; r++)
                atomicAdd(&num[(size_t)(mg + r) * HH + hg], acc[im][ie][r]);
        }
    }
}

// ---------- K3: out = concat(num/den, x) @ W_cons^T + b_cons ----------
// grid (32 mblk, 16 hblk), block 256. Tile 64x64, K=2048. (unchanged)
__global__ __launch_bounds__(256) void k3_final(const float* __restrict__ num,
                                                const float* __restrict__ den,
                                                const ushort_t* __restrict__ xb,
                                                const float* __restrict__ Wc,
                                                const float* __restrict__ bc,
                                                float* __restrict__ out) {
    __shared__ ushort_t sA[64][40];
    __shared__ ushort_t sB[64][40];
    const int m0 = blockIdx.x * 64;
    const int h0 = blockIdx.y * 64;
    const int t = threadIdx.x;
    const int wv = t >> 6, l = t & 63, ml = l & 15, quad = l >> 4;
    const int wm = (wv & 1) * 32, we = (wv >> 1) * 32;
    const int sr = t >> 2;
    const int sc = (t & 3) * 8;
    const float rden = 1.0f / den[m0 + sr];

    floatx4 acc[2][2];
#pragma unroll
    for (int i = 0; i < 2; i++)
#pragma unroll
        for (int j = 0; j < 2; j++) acc[i][j] = (floatx4)(0.0f);

    for (int k0 = 0; k0 < KC; k0 += 32) {
        union { uint4 v; ushort_t u[8]; } aw;
        if (k0 < HH) {
            const float* np = num + (size_t)(m0 + sr) * HH + k0 + sc;
            float4 v0 = *(const float4*)(np);
            float4 v1 = *(const float4*)(np + 4);
            aw.u[0] = f2b(v0.x * rden); aw.u[1] = f2b(v0.y * rden);
            aw.u[2] = f2b(v0.z * rden); aw.u[3] = f2b(v0.w * rden);
            aw.u[4] = f2b(v1.x * rden); aw.u[5] = f2b(v1.y * rden);
            aw.u[6] = f2b(v1.z * rden); aw.u[7] = f2b(v1.w * rden);
        } else {
            aw.v = *(const uint4*)(xb + (size_t)(m0 + sr) * HH + (k0 - HH) + sc);
        }
        union { uint4 v; ushort_t u[8]; } bw;
        {
            const float* wp = Wc + (size_t)(h0 + sr) * KC + k0 + sc;
            float4 w0 = *(const float4*)(wp);
            float4 w1 = *(const float4*)(wp + 4);
            bw.u[0] = f2b(w0.x); bw.u[1] = f2b(w0.y); bw.u[2] = f2b(w0.z); bw.u[3] = f2b(w0.w);
            bw.u[4] = f2b(w1.x); bw.u[5] = f2b(w1.y); bw.u[6] = f2b(w1.z); bw.u[7] = f2b(w1.w);
        }
        __syncthreads();
        *(uint4*)&sA[sr][sc] = aw.v;
        *(uint4*)&sB[sr][sc] = bw.v;
        __syncthreads();

        short8 a0 = *(const short8*)&sA[wm + ml][quad * 8];
        short8 a1 = *(const short8*)&sA[wm + 16 + ml][quad * 8];
        short8 b0 = *(const short8*)&sB[we + ml][quad * 8];
        short8 b1 = *(const short8*)&sB[we + 16 + ml][quad * 8];
        acc[0][0] = __builtin_amdgcn_mfma_f32_16x16x32_bf16(a0, b0, acc[0][0], 0, 0, 0);
        acc[0][1] = __builtin_amdgcn_mfma_f32_16x16x32_bf16(a0, b1, acc[0][1], 0, 0, 0);
        acc[1][0] = __builtin_amdgcn_mfma_f32_16x16x32_bf16(a1, b0, acc[1][0], 0, 0, 0);
        acc[1][1] = __builtin_amdgcn_mfma_f32_16x16x32_bf16(a1, b1, acc[1][1], 0, 0, 0);
    }

#pragma unroll
    for (int ie = 0; ie < 2; ie++) {
        const int hg = h0 + we + ie * 16 + ml;
        const float bb = bc[hg];
#pragma unroll
        for (int im = 0; im < 2; im++) {
            const int mg = m0 + wm + im * 16 + quad * 4;
#pragma unroll
            for (int r = 0; r < 4; r++)
                out[(size_t)(mg + r) * HH + hg] = acc[im][ie][r] + bb;
        }
    }
}

// ---------- sentinel: workspace too small (diagnosable via absmax ~12345) ----------
__global__ void ws_too_small_sentinel(float* __restrict__ out, int n) {
    int i = blockIdx.x * 256 + threadIdx.x;
    if (i < n) out[i] = -12345.0f;
}

extern "C" void kernel_launch(void* const* d_in, const int* in_sizes, int n_in,
                              void* d_out, int out_size, void* d_ws, size_t ws_size,
                              hipStream_t stream) {
    const float* x      = (const float*)d_in[0];
    const float* W_epi  = (const float*)d_in[1];
    const float* b_epi  = (const float*)d_in[2];
    const float* epimem = (const float*)d_in[3];
    // d_in[4..6] = W_sem, b_sem, sem_mem : dead code in the reference, skipped
    const float* W_cons = (const float*)d_in[7];
    const float* b_cons = (const float*)d_in[8];
    float* out = (float*)d_out;

    const size_t XB_OFF   = 0;
    const size_t XB_B     = (size_t)MM * HH * 2;       //   4 MiB
    const size_t P_OFF    = XB_OFF + XB_B;
    const size_t P_B      = (size_t)MM * EH * 2;       //  ~98 MiB (one E-half)
    const size_t BANK_OFF = P_OFF + P_B;
    const size_t BANK_B   = (size_t)EH * HH * 2;       //  ~49 MiB (Wb then mT, aliased)
    const size_t NUM_OFF  = BANK_OFF + BANK_B;
    const size_t NUM_B    = (size_t)MM * HH * 4;       //   8 MiB
    const size_t DEN_OFF  = NUM_OFF + NUM_B;
    const size_t DEN_B    = (size_t)MM * 4;
    const size_t NEED     = DEN_OFF + DEN_B;           // ~159 MiB total

    if (ws_size < NEED) {
        ws_too_small_sentinel<<<(out_size + 255) / 256, 256, 0, stream>>>(out, out_size);
        return;
    }

    ushort_t* xb   = (ushort_t*)((char*)d_ws + XB_OFF);
    ushort_t* P    = (ushort_t*)((char*)d_ws + P_OFF);
    ushort_t* bank = (ushort_t*)((char*)d_ws + BANK_OFF);
    float*    num  = (float*)((char*)d_ws + NUM_OFF);
    float*    den  = (float*)((char*)d_ws + DEN_OFF);

    hipMemsetAsync(num, 0, NUM_B, stream);
    hipMemsetAsync(den, 0, DEN_B, stream);
    k0_convert_x<<<(MM * HH) / (256 * 8), 256, 0, stream>>>(x, xb);

    for (int half = 0; half < 2; ++half) {
        const int ebase = half * EH;
        kw_conv<<<(EH * HH) / (8 * 256), 256, 0, stream>>>(W_epi, bank, ebase);
        g1_logits<<<dim3(MM / 128, EH / 128), 256, 0, stream>>>(xb, bank, b_epi, P, den, ebase);
        km_transpose<<<dim3(EH / 64, HH / 64), 256, 0, stream>>>(epimem, bank, ebase);
        g2_pv<<<dim3(MM / 128, HH / 128, 4), 256, 0, stream>>>(P, bank, num);
    }

    k3_final<<<dim3(MM / 64, HH / 64), 256, 0, stream>>>(num, den, xb, W_cons, b_cons, out);
}